// Round 6
// baseline (269.904 us; speedup 1.0000x reference)
//
#include <hip/hip_runtime.h>

// R6: gemm+collect with (1) no global atomics in loop (per-block region, LDS
// counter), (2) depth-2 register prefetch (zero exposed HBM latency at stage),
// (3) HW v_cvt_pk_bf16_f32 packing, (4) init kernel folded into gemm.
#define BROWS 256
#define NCOLS 131072
#define DDIM  128
#define K     5
#define MARGIN 0.3f

#define NBLK  512                // gemm grid: 2 blocks/CU
#define CPB   (NCOLS / NBLK)     // 256 cols per block
#define NIT   (CPB / 16)         // 16 iters of 16 cols
#define ZGATE 3.4f               // per-row gate: E[hits/row] ~ 44
#define RCAP  96                 // per-block region cap: hits/block ~ Poisson(22)
#define YSTR  68                 // ybf col stride in words (64 data + 4 pad)

typedef __attribute__((ext_vector_type(8))) __bf16 bf16x8;
typedef __attribute__((ext_vector_type(4))) float f32x4;
typedef __attribute__((ext_vector_type(4))) unsigned int u32x4;

// two fp32 -> packed bf16 word (lo=a, hi=b)
__device__ __forceinline__ unsigned pack_bf16(float a, float b) {
#if defined(__has_builtin) && __has_builtin(__builtin_amdgcn_cvt_pk_bf16_f32)
    auto r = __builtin_amdgcn_cvt_pk_bf16_f32(a, b);   // gfx950 V_CVT_PK_BF16_F32
    return __builtin_bit_cast(unsigned, r);
#else
    unsigned ua = __float_as_uint(a), ub = __float_as_uint(b);
    unsigned ra = (ua + 0x7fffu + ((ua >> 16) & 1u)) >> 16;
    unsigned rb = (ub + 0x7fffu + ((ub >> 16) & 1u)) & 0xffff0000u;
    return ra | rb;
#endif
}

__device__ __forceinline__ u32x4 pack8(const float4& a, const float4& b) {
    u32x4 t;
    t[0] = pack_bf16(a.x, a.y); t[1] = pack_bf16(a.z, a.w);
    t[2] = pack_bf16(b.x, b.y); t[3] = pack_bf16(b.z, b.w);
    return t;
}

// ---- Pass 1: bf16 MFMA gemm + adaptive-threshold collection -----------------
__global__ __launch_bounds__(256, 2) void gemm_collect_kernel(
    const float* __restrict__ x, const float* __restrict__ y,
    uint2* __restrict__ regions, int* __restrict__ nbs, float* __restrict__ outz)
{
    __shared__ unsigned ybf[2][16 * YSTR];   // double-buffered bf16 y tile
    __shared__ int lcnt;

    const int tid   = threadIdx.x;
    const int lane  = tid & 63;
    const int quad  = lane >> 4;
    const int l15   = lane & 15;
    const int wrow0 = tid & 192;             // wave_id*64
    const int col0  = blockIdx.x * CPB;

    if (blockIdx.x == 0 && tid == 0) outz[0] = 0.f;   // replaces memset dispatch
    if (tid == 0) lcnt = 0;

    // A fragments (x fp32 -> bf16, register-resident) + row-norm partials.
    // A[m=l15][k=quad*8+j]; this lane holds quad's 32 floats of row wrow0+mt*16+l15.
    bf16x8 af[4][4];
    float nrm[4];
#pragma unroll
    for (int mt = 0; mt < 4; ++mt) {
        const float* xp = x + (size_t)(wrow0 + mt * 16 + l15) * DDIM + quad * 8;
        float s2 = 0.f;
#pragma unroll
        for (int s = 0; s < 4; ++s) {
            const float4 a = *(const float4*)(xp + s * 32);
            const float4 b = *(const float4*)(xp + s * 32 + 4);
            s2 = fmaf(a.x, a.x, s2); s2 = fmaf(a.y, a.y, s2);
            s2 = fmaf(a.z, a.z, s2); s2 = fmaf(a.w, a.w, s2);
            s2 = fmaf(b.x, b.x, s2); s2 = fmaf(b.y, b.y, s2);
            s2 = fmaf(b.z, b.z, s2); s2 = fmaf(b.w, b.w, s2);
            const u32x4 t = pack8(a, b);
            af[mt][s] = __builtin_bit_cast(bf16x8, t);
        }
        nrm[mt] = s2;
    }
    // full row norm: sum the 4 quads (lanes sharing l15) -> thr for row ..+l15
    float myThr[4];
#pragma unroll
    for (int mt = 0; mt < 4; ++mt) {
        float s2 = nrm[mt];
        s2 += __shfl_xor(s2, 16);
        s2 += __shfl_xor(s2, 32);
        myThr[mt] = ZGATE * sqrtf(s2);
    }
    // redistribute to acc layout: lane needs thr of rows wrow0+mt*16+(quad*4+r),
    // held by lane (quad*4+r) (its l15 == quad*4+r, quad bits 0)
    float thrv[16];
#pragma unroll
    for (int mt = 0; mt < 4; ++mt)
#pragma unroll
        for (int r = 0; r < 4; ++r)
            thrv[mt * 4 + r] = __shfl(myThr[mt], quad * 4 + r);

    // staging: thread (sc,sj) loads 8 fp32 of y row col0+sc, converts, writes one b128
    const int sc = tid >> 4, sj = tid & 15;
    const float* ysrc = y + (size_t)(col0 + sc) * DDIM + sj * 8;
    const unsigned sdst = sc * YSTR + sj * 4;
    const unsigned frag_off = l15 * YSTR + quad * 4;

    // depth-2 prefetch: g[t&1] holds tile t's 8 floats
    float4 ga[2], gb[2];
    ga[0] = *(const float4*)(ysrc);
    gb[0] = *(const float4*)(ysrc + 4);
    ga[1] = *(const float4*)(ysrc + 16 * DDIM);
    gb[1] = *(const float4*)(ysrc + 16 * DDIM + 4);
    *(u32x4*)(&ybf[0][0] + sdst) = pack8(ga[0], gb[0]);   // stage tile 0

    for (int it = 0; it < NIT; ++it) {
        if (it + 2 < NIT) {                  // load tile it+2 into freed slot
            const float* yn = ysrc + (size_t)(it + 2) * 16 * DDIM;
            ga[it & 1] = *(const float4*)(yn);
            gb[it & 1] = *(const float4*)(yn + 4);
        }
        __syncthreads();                     // ybf[it&1] staged; prior reads of other buf done

        const unsigned* yb = &ybf[it & 1][0];
        bf16x8 bfrag[4];
#pragma unroll
        for (int s = 0; s < 4; ++s)
            bfrag[s] = __builtin_bit_cast(bf16x8, *(const u32x4*)(yb + frag_off + s * 16));

        f32x4 acc[4];
#pragma unroll
        for (int mt = 0; mt < 4; ++mt) acc[mt] = (f32x4){0.f, 0.f, 0.f, 0.f};
#pragma unroll
        for (int s = 0; s < 4; ++s)
#pragma unroll
            for (int mt = 0; mt < 4; ++mt)
                acc[mt] = __builtin_amdgcn_mfma_f32_16x16x32_bf16(af[mt][s], bfrag[s], acc[mt], 0, 0, 0);

        if (it + 1 < NIT)                    // stage tile it+1 (loaded a full iter ago)
            *(u32x4*)(&ybf[(it + 1) & 1][0] + sdst) = pack8(ga[(it + 1) & 1], gb[(it + 1) & 1]);

        // gate: lane's 16 acc values share col = col0+it*16+l15; body ~30% of wave-iters
        float m = -1.f;
#pragma unroll
        for (int mt = 0; mt < 4; ++mt)
#pragma unroll
            for (int r = 0; r < 4; ++r)
                m = fmaxf(m, acc[mt][r] - thrv[mt * 4 + r]);
        if (m > 0.f) {
            const int col = col0 + it * 16 + l15;
#pragma unroll
            for (int mt = 0; mt < 4; ++mt)
#pragma unroll
                for (int r = 0; r < 4; ++r) {
                    const float v = acc[mt][r];
                    if (v > thrv[mt * 4 + r]) {
                        const int idx = atomicAdd(&lcnt, 1);   // LDS atomic, ~40 cyc
                        if (idx < RCAP) {
                            const int row = wrow0 + mt * 16 + quad * 4 + r;
                            regions[blockIdx.x * RCAP + idx] =
                                make_uint2(__float_as_uint(v), ((unsigned)row << 17) | (unsigned)col);
                        }
                    }
                }
        }
    }

    __syncthreads();
    if (tid == 0) nbs[blockIdx.x] = lcnt;    // publish count once per block
}

// ---- helpers ----------------------------------------------------------------
__device__ __forceinline__ void insert5(float* t5, float v) {
    if (v > t5[K - 1]) {
        float nv = v;
#pragma unroll
        for (int p = 0; p < K; ++p) {
            const bool gt = nv > t5[p];
            const float tv = t5[p];
            if (gt) { t5[p] = nv; nv = tv; }
        }
    }
}

__device__ __forceinline__ void merge5(float* __restrict__ t5, const float* __restrict__ src) {
#pragma unroll
    for (int p = 0; p < K; ++p) insert5(t5, src[p]);
}

__device__ __forceinline__ float epilogue(const float* t5, float sp) {
    float loss[K], logit[K];
#pragma unroll
    for (int p = 0; p < K; ++p) {
        loss[p]  = fmaxf(0.f, t5[p] - sp + MARGIN);
        logit[p] = (loss[p] != 0.f) ? t5[p] : 0.f;   // sim_n * mask, as reference
    }
    float mx = logit[0];
#pragma unroll
    for (int p = 1; p < K; ++p) mx = fmaxf(mx, logit[p]);
    float den = 0.f, num = 0.f;
#pragma unroll
    for (int p = 0; p < K; ++p) {
        const float e = __expf(logit[p] - mx);
        den += e;
        num += loss[p] * e;
    }
    return num / den;
}

// ---- Pass 2: per-row top-5 from region scan + loss --------------------------
__global__ __launch_bounds__(256) void reduce_kernel(
    const float* __restrict__ x, const float* __restrict__ y,
    const int* __restrict__ pos,
    const uint2* __restrict__ regions, const int* __restrict__ nbs,
    int* __restrict__ flag, float* __restrict__ out)
{
    const int row = blockIdx.x;
    const int tid = threadIdx.x;
    __shared__ float sred[256];
    __shared__ float sv[256 * K];
    __shared__ int sover;
    if (tid == 0) sover = 0;

    // sim_p = fp32 dot(x[row], y[pos[row]])
    const int prow = pos[row];
    float p = 0.f;
    if (tid < DDIM) p = x[row * DDIM + tid] * y[(size_t)prow * DDIM + tid];
    sred[tid] = p;
    __syncthreads();
    for (int s = 128; s >= 1; s >>= 1) {
        if (tid < s) sred[tid] += sred[tid + s];
        __syncthreads();
    }

    // scan all 512 regions (384 KB total, L2-resident); keep entries for my row
    float t5[K];
#pragma unroll
    for (int q = 0; q < K; ++q) t5[q] = -3.0e38f;
    int over = 0;
    for (int reg = tid; reg < NBLK; reg += 256) {
        int nb = nbs[reg];
        if (nb > RCAP) { over = 1; nb = RCAP; }
        const uint2* rp = regions + (size_t)reg * RCAP;
        for (int i = 0; i < nb; ++i) {
            const uint2 e = rp[i];
            const int r = (int)(e.y >> 17), c = (int)(e.y & 0x1FFFFu);
            if (r == row && c != prow) insert5(t5, __uint_as_float(e.x));
        }
    }
    if (over) sover = 1;   // same-value race OK

#pragma unroll
    for (int q = 0; q < K; ++q) sv[tid * K + q] = t5[q];
    __syncthreads();
    for (int s = 128; s >= 1; s >>= 1) {
        if (tid < s) {
            merge5(t5, &sv[(tid + s) * K]);
#pragma unroll
            for (int q = 0; q < K; ++q) sv[tid * K + q] = t5[q];
        }
        __syncthreads();
    }

    if (tid == 0) {
        // exact iff no region overflow anywhere and >=5 survivors for this row
        const bool ok = (sover == 0) && (t5[K - 1] > -1.0e38f);
        flag[row] = ok ? 0 : 1;
        if (ok) atomicAdd(out, epilogue(t5, sred[0]) * (1.0f / (BROWS * K)));
    }
}

// ---- Pass 3: exactness insurance — brute-force flagged rows -----------------
__global__ __launch_bounds__(256) void fallback_kernel(
    const float* __restrict__ x, const float* __restrict__ y,
    const int* __restrict__ pos, const int* __restrict__ flag,
    float* __restrict__ out)
{
    const int row = blockIdx.x;
    if (flag[row] == 0) return;              // normal case: immediate exit
    const int tid = threadIdx.x;
    const int prow = pos[row];
    __shared__ float xr[DDIM];
    __shared__ float sv[256 * K];
    if (tid < DDIM) xr[tid] = x[row * DDIM + tid];
    __syncthreads();

    float t5[K];
#pragma unroll
    for (int q = 0; q < K; ++q) t5[q] = -3.0e38f;
    for (int col = tid; col < NCOLS; col += 256) {
        if (col == prow) continue;
        const float* yp = y + (size_t)col * DDIM;
        float d = 0.f;
        for (int k = 0; k < DDIM; ++k) d = fmaf(xr[k], yp[k], d);
        insert5(t5, d);
    }
#pragma unroll
    for (int q = 0; q < K; ++q) sv[tid * K + q] = t5[q];
    __syncthreads();
    for (int s = 128; s >= 1; s >>= 1) {
        if (tid < s) {
            merge5(t5, &sv[(tid + s) * K]);
#pragma unroll
            for (int q = 0; q < K; ++q) sv[tid * K + q] = t5[q];
        }
        __syncthreads();
    }
    if (tid == 0) {
        float sp = 0.f;
        const float* yp = y + (size_t)prow * DDIM;
        for (int k = 0; k < DDIM; ++k) sp = fmaf(xr[k], yp[k], sp);
        atomicAdd(out, epilogue(t5, sp) * (1.0f / (BROWS * K)));
    }
}

extern "C" void kernel_launch(void* const* d_in, const int* in_sizes, int n_in,
                              void* d_out, int out_size, void* d_ws, size_t ws_size,
                              hipStream_t stream) {
    const float* x  = (const float*)d_in[0];   // [256,128] fp32
    const float* y  = (const float*)d_in[1];   // [131072,128] fp32
    // d_in[2] (target) is redundant (one-hot of pos_inds) — never read.
    const int* pos  = (const int*)d_in[3];     // [256] int32
    // d_in[4] (num_neg) fixed at 5 — compile-time K.

    uint2* regions = (uint2*)d_ws;                      // 512*96*8 B = 384 KB
    int*   nbs     = (int*)(regions + (size_t)NBLK * RCAP);  // 512 ints
    int*   flag    = nbs + NBLK;                        // 256 ints

    gemm_collect_kernel<<<dim3(NBLK), 256, 0, stream>>>(x, y, regions, nbs, (float*)d_out);
    reduce_kernel<<<dim3(BROWS), 256, 0, stream>>>(x, y, pos, regions, nbs, flag, (float*)d_out);
    fallback_kernel<<<dim3(BROWS), 256, 0, stream>>>(x, y, pos, flag, (float*)d_out);
}

// Round 7
// 246.493 us; speedup vs baseline: 1.0950x; 1.0950x over previous
//
#include <hip/hip_runtime.h>

// R7: gemm preloads its ENTIRE y-slice to registers in the prologue (32
// back-to-back global loads/lane, one latency exposure), fully-unrolled main
// loop stages LDS from registers only (static reg indexing — R6's dynamic
// ga[it&1] regression reverted). Fallback merged into reduce (one dispatch).
#define BROWS 256
#define NCOLS 131072
#define DDIM  128
#define K     5
#define MARGIN 0.3f

#define NBLK  512                // gemm grid: 2 blocks/CU
#define CPB   (NCOLS / NBLK)     // 256 cols per block
#define NIT   (CPB / 16)         // 16 iters of 16 cols
#define ZGATE 3.4f               // per-row gate: E[hits/row] ~ 44
#define RCAP  96                 // per-block region cap: hits/block ~ Poisson(22)
#define YSTR  68                 // ybf col stride in words (64 data + 4 pad)

typedef __attribute__((ext_vector_type(8))) __bf16 bf16x8;
typedef __attribute__((ext_vector_type(4))) float f32x4;
typedef __attribute__((ext_vector_type(4))) unsigned int u32x4;

// two fp32 -> packed bf16 word (lo=a, hi=b)
__device__ __forceinline__ unsigned pack_bf16(float a, float b) {
#if defined(__has_builtin) && __has_builtin(__builtin_amdgcn_cvt_pk_bf16_f32)
    auto r = __builtin_amdgcn_cvt_pk_bf16_f32(a, b);   // gfx950 V_CVT_PK_BF16_F32
    return __builtin_bit_cast(unsigned, r);
#else
    unsigned ua = __float_as_uint(a), ub = __float_as_uint(b);
    unsigned ra = (ua + 0x7fffu + ((ua >> 16) & 1u)) >> 16;
    unsigned rb = (ub + 0x7fffu + ((ub >> 16) & 1u)) & 0xffff0000u;
    return ra | rb;
#endif
}

__device__ __forceinline__ u32x4 pack8(const float4& a, const float4& b) {
    u32x4 t;
    t[0] = pack_bf16(a.x, a.y); t[1] = pack_bf16(a.z, a.w);
    t[2] = pack_bf16(b.x, b.y); t[3] = pack_bf16(b.z, b.w);
    return t;
}

// ---- Pass 1: bf16 MFMA gemm + adaptive-threshold collection -----------------
__global__ __launch_bounds__(256, 2) void gemm_collect_kernel(
    const float* __restrict__ x, const float* __restrict__ y,
    uint2* __restrict__ regions, int* __restrict__ nbs, float* __restrict__ outz)
{
    __shared__ unsigned ybf[2][16 * YSTR];   // double-buffered bf16 y tile, 2x4.25 KB
    __shared__ int lcnt;

    const int tid   = threadIdx.x;
    const int lane  = tid & 63;
    const int quad  = lane >> 4;
    const int l15   = lane & 15;
    const int wrow0 = tid & 192;             // wave_id*64
    const int col0  = blockIdx.x * CPB;

    if (blockIdx.x == 0 && tid == 0) outz[0] = 0.f;   // replaces memset dispatch
    if (tid == 0) lcnt = 0;

    // A fragments (x fp32 -> bf16, register-resident) + row-norm partials.
    bf16x8 af[4][4];
    float nrm[4];
#pragma unroll
    for (int mt = 0; mt < 4; ++mt) {
        const float* xp = x + (size_t)(wrow0 + mt * 16 + l15) * DDIM + quad * 8;
        float s2 = 0.f;
#pragma unroll
        for (int s = 0; s < 4; ++s) {
            const float4 a = *(const float4*)(xp + s * 32);
            const float4 b = *(const float4*)(xp + s * 32 + 4);
            s2 = fmaf(a.x, a.x, s2); s2 = fmaf(a.y, a.y, s2);
            s2 = fmaf(a.z, a.z, s2); s2 = fmaf(a.w, a.w, s2);
            s2 = fmaf(b.x, b.x, s2); s2 = fmaf(b.y, b.y, s2);
            s2 = fmaf(b.z, b.z, s2); s2 = fmaf(b.w, b.w, s2);
            const u32x4 t = pack8(a, b);
            af[mt][s] = __builtin_bit_cast(bf16x8, t);
        }
        nrm[mt] = s2;
    }
    float myThr[4];
#pragma unroll
    for (int mt = 0; mt < 4; ++mt) {
        float s2 = nrm[mt];
        s2 += __shfl_xor(s2, 16);
        s2 += __shfl_xor(s2, 32);
        myThr[mt] = ZGATE * sqrtf(s2);
    }
    float thrv[16];
#pragma unroll
    for (int mt = 0; mt < 4; ++mt)
#pragma unroll
        for (int r = 0; r < 4; ++r)
            thrv[mt * 4 + r] = __shfl(myThr[mt], quad * 4 + r);

    // ---- preload THIS BLOCK'S ENTIRE y-slice into registers (bf16-packed).
    // Thread (sc,sj) owns col0+sc + 16*t, dims sj*8..sj*8+7 for every tile t.
    // 32 independent float4 loads issued by the scheduler with no in-loop
    // vmcnt coupling; steady-state cost = 64 VGPRs of packed bf16.
    const int sc = tid >> 4, sj = tid & 15;
    const float* ysrc = y + (size_t)(col0 + sc) * DDIM + sj * 8;
    u32x4 yw[NIT];
#pragma unroll
    for (int t = 0; t < NIT; ++t) {
        const float4 a = *(const float4*)(ysrc + (size_t)t * 16 * DDIM);
        const float4 b = *(const float4*)(ysrc + (size_t)t * 16 * DDIM + 4);
        yw[t] = pack8(a, b);
    }

    const unsigned sdst = sc * YSTR + sj * 4;
    const unsigned frag_off = l15 * YSTR + quad * 4;
    *(u32x4*)(&ybf[0][0] + sdst) = yw[0];   // stage tile 0

    // fully unrolled: all yw[] indices compile-time constant (no scratch)
#pragma unroll
    for (int it = 0; it < NIT; ++it) {
        __syncthreads();                     // ybf[it&1] staged; prior reads of other buf done

        const unsigned* yb = &ybf[it & 1][0];
        bf16x8 bfrag[4];
#pragma unroll
        for (int s = 0; s < 4; ++s)
            bfrag[s] = __builtin_bit_cast(bf16x8, *(const u32x4*)(yb + frag_off + s * 16));

        f32x4 acc[4];
#pragma unroll
        for (int mt = 0; mt < 4; ++mt) acc[mt] = (f32x4){0.f, 0.f, 0.f, 0.f};
#pragma unroll
        for (int s = 0; s < 4; ++s)
#pragma unroll
            for (int mt = 0; mt < 4; ++mt)
                acc[mt] = __builtin_amdgcn_mfma_f32_16x16x32_bf16(af[mt][s], bfrag[s], acc[mt], 0, 0, 0);

        if (it + 1 < NIT)                    // stage next tile straight from registers
            *(u32x4*)(&ybf[(it + 1) & 1][0] + sdst) = yw[it + 1];

        // gate: lane's 16 acc values share col = col0+it*16+l15
        float m = -1.f;
#pragma unroll
        for (int mt = 0; mt < 4; ++mt)
#pragma unroll
            for (int r = 0; r < 4; ++r)
                m = fmaxf(m, acc[mt][r] - thrv[mt * 4 + r]);
        if (m > 0.f) {
            const int col = col0 + it * 16 + l15;
#pragma unroll
            for (int mt = 0; mt < 4; ++mt)
#pragma unroll
                for (int r = 0; r < 4; ++r) {
                    const float v = acc[mt][r];
                    if (v > thrv[mt * 4 + r]) {
                        const int idx = atomicAdd(&lcnt, 1);   // LDS atomic
                        if (idx < RCAP) {
                            const int row = wrow0 + mt * 16 + quad * 4 + r;
                            regions[blockIdx.x * RCAP + idx] =
                                make_uint2(__float_as_uint(v), ((unsigned)row << 17) | (unsigned)col);
                        }
                    }
                }
        }
    }

    __syncthreads();
    if (tid == 0) nbs[blockIdx.x] = lcnt;    // publish count once per block
}

// ---- helpers ----------------------------------------------------------------
__device__ __forceinline__ void insert5(float* t5, float v) {
    if (v > t5[K - 1]) {
        float nv = v;
#pragma unroll
        for (int p = 0; p < K; ++p) {
            const bool gt = nv > t5[p];
            const float tv = t5[p];
            if (gt) { t5[p] = nv; nv = tv; }
        }
    }
}

__device__ __forceinline__ void merge5(float* __restrict__ t5, const float* __restrict__ src) {
#pragma unroll
    for (int p = 0; p < K; ++p) insert5(t5, src[p]);
}

__device__ __forceinline__ float epilogue(const float* t5, float sp) {
    float loss[K], logit[K];
#pragma unroll
    for (int p = 0; p < K; ++p) {
        loss[p]  = fmaxf(0.f, t5[p] - sp + MARGIN);
        logit[p] = (loss[p] != 0.f) ? t5[p] : 0.f;   // sim_n * mask, as reference
    }
    float mx = logit[0];
#pragma unroll
    for (int p = 1; p < K; ++p) mx = fmaxf(mx, logit[p]);
    float den = 0.f, num = 0.f;
#pragma unroll
    for (int p = 0; p < K; ++p) {
        const float e = __expf(logit[p] - mx);
        den += e;
        num += loss[p] * e;
    }
    return num / den;
}

// ---- Pass 2: per-row top-5 + loss; exact fallback merged in ----------------
__global__ __launch_bounds__(256) void reduce_kernel(
    const float* __restrict__ x, const float* __restrict__ y,
    const int* __restrict__ pos,
    const uint2* __restrict__ regions, const int* __restrict__ nbs,
    float* __restrict__ out)
{
    const int row = blockIdx.x;
    const int tid = threadIdx.x;
    __shared__ float sred[256];
    __shared__ float sv[256 * K];
    __shared__ float xr[DDIM];
    __shared__ int sover, sok;
    if (tid == 0) { sover = 0; sok = 0; }

    // sim_p = fp32 dot(x[row], y[pos[row]]); also stage x row for fallback
    const int prow = pos[row];
    float p = 0.f;
    if (tid < DDIM) {
        const float xv = x[row * DDIM + tid];
        xr[tid] = xv;
        p = xv * y[(size_t)prow * DDIM + tid];
    }
    sred[tid] = p;
    __syncthreads();                          // also publishes sover/sok init
    for (int s = 128; s >= 1; s >>= 1) {
        if (tid < s) sred[tid] += sred[tid + s];
        __syncthreads();
    }
    // sred[0] = sim_p from here on (tree writes only tid<s slots, [0] holds sum)

    // scan all 512 regions (384 KB, L2-resident); keep entries for my row
    float t5[K];
#pragma unroll
    for (int q = 0; q < K; ++q) t5[q] = -3.0e38f;
    int over = 0;
    for (int reg = tid; reg < NBLK; reg += 256) {
        int nb = nbs[reg];
        if (nb > RCAP) { over = 1; nb = RCAP; }
        const uint2* rp = regions + (size_t)reg * RCAP;
        for (int i = 0; i < nb; ++i) {
            const uint2 e = rp[i];
            const int r = (int)(e.y >> 17), c = (int)(e.y & 0x1FFFFu);
            if (r == row && c != prow) insert5(t5, __uint_as_float(e.x));
        }
    }
    if (over) sover = 1;   // same-value race OK

#pragma unroll
    for (int q = 0; q < K; ++q) sv[tid * K + q] = t5[q];
    __syncthreads();
    for (int s = 128; s >= 1; s >>= 1) {
        if (tid < s) {
            merge5(t5, &sv[(tid + s) * K]);
#pragma unroll
            for (int q = 0; q < K; ++q) sv[tid * K + q] = t5[q];
        }
        __syncthreads();
    }

    if (tid == 0) {
        const bool ok = (sover == 0) && (t5[K - 1] > -1.0e38f);
        sok = ok ? 1 : 0;
        if (ok) atomicAdd(out, epilogue(t5, sred[0]) * (1.0f / (BROWS * K)));
    }
    __syncthreads();
    if (sok) return;

    // ---- exactness insurance: brute-force this row (dormant in practice) ----
    float b5[K];
#pragma unroll
    for (int q = 0; q < K; ++q) b5[q] = -3.0e38f;
    for (int col = tid; col < NCOLS; col += 256) {
        if (col == prow) continue;
        const float* yp = y + (size_t)col * DDIM;
        float d = 0.f;
        for (int k = 0; k < DDIM; ++k) d = fmaf(xr[k], yp[k], d);
        insert5(b5, d);
    }
#pragma unroll
    for (int q = 0; q < K; ++q) sv[tid * K + q] = b5[q];
    __syncthreads();
    for (int s = 128; s >= 1; s >>= 1) {
        if (tid < s) {
            merge5(b5, &sv[(tid + s) * K]);
#pragma unroll
            for (int q = 0; q < K; ++q) sv[tid * K + q] = b5[q];
        }
        __syncthreads();
    }
    if (tid == 0) atomicAdd(out, epilogue(b5, sred[0]) * (1.0f / (BROWS * K)));
}

extern "C" void kernel_launch(void* const* d_in, const int* in_sizes, int n_in,
                              void* d_out, int out_size, void* d_ws, size_t ws_size,
                              hipStream_t stream) {
    const float* x  = (const float*)d_in[0];   // [256,128] fp32
    const float* y  = (const float*)d_in[1];   // [131072,128] fp32
    // d_in[2] (target) is redundant (one-hot of pos_inds) — never read.
    const int* pos  = (const int*)d_in[3];     // [256] int32
    // d_in[4] (num_neg) fixed at 5 — compile-time K.

    uint2* regions = (uint2*)d_ws;                           // 512*96*8 B = 384 KB
    int*   nbs     = (int*)(regions + (size_t)NBLK * RCAP);  // 512 ints

    gemm_collect_kernel<<<dim3(NBLK), 256, 0, stream>>>(x, y, regions, nbs, (float*)d_out);
    reduce_kernel<<<dim3(BROWS), 256, 0, stream>>>(x, y, pos, regions, nbs, (float*)d_out);
}

// Round 8
// 239.233 us; speedup vs baseline: 1.1282x; 1.0303x over previous
//
#include <hip/hip_runtime.h>

// R8 DIAGNOSTIC: identical structure to the best kernel (R5-style depth-1
// LDS-staged gemm + R6/R7 collect), but grid 256 instead of 512 (1 block/CU,
// CPB=512, NIT=32). Purpose: per-block work doubles, so if the gemm is
// structure/latency-bound it lands at ~140-150us and finally becomes VISIBLE
// in the top-5 profile window (fills occupy ~77-79us); if it's HBM-bound it
// stays ~11-15us and the total is unchanged -> residual is harness overhead.
#define BROWS 256
#define NCOLS 131072
#define DDIM  128
#define K     5
#define MARGIN 0.3f

#define NBLK  256                // 1 block/CU (diagnostic; was 512)
#define CPB   (NCOLS / NBLK)     // 512 cols per block
#define NIT   (CPB / 16)         // 32 iters of 16 cols
#define ZGATE 3.4f               // per-row gate: E[hits/row] ~ 44
#define RCAP  128                // per-block cap: hits/block ~ Poisson(44)
#define YSTR  68                 // ybf col stride in words (64 data + 4 pad)

typedef __attribute__((ext_vector_type(8))) __bf16 bf16x8;
typedef __attribute__((ext_vector_type(4))) float f32x4;
typedef __attribute__((ext_vector_type(4))) unsigned int u32x4;

// two fp32 -> packed bf16 word (lo=a, hi=b)
__device__ __forceinline__ unsigned pack_bf16(float a, float b) {
#if defined(__has_builtin) && __has_builtin(__builtin_amdgcn_cvt_pk_bf16_f32)
    auto r = __builtin_amdgcn_cvt_pk_bf16_f32(a, b);   // gfx950 V_CVT_PK_BF16_F32
    return __builtin_bit_cast(unsigned, r);
#else
    unsigned ua = __float_as_uint(a), ub = __float_as_uint(b);
    unsigned ra = (ua + 0x7fffu + ((ua >> 16) & 1u)) >> 16;
    unsigned rb = (ub + 0x7fffu + ((ub >> 16) & 1u)) & 0xffff0000u;
    return ra | rb;
#endif
}

__device__ __forceinline__ u32x4 pack8(const float4& a, const float4& b) {
    u32x4 t;
    t[0] = pack_bf16(a.x, a.y); t[1] = pack_bf16(a.z, a.w);
    t[2] = pack_bf16(b.x, b.y); t[3] = pack_bf16(b.z, b.w);
    return t;
}

// ---- Pass 1: bf16 MFMA gemm + adaptive-threshold collection -----------------
__global__ __launch_bounds__(256, 2) void gemm_collect_kernel(
    const float* __restrict__ x, const float* __restrict__ y,
    uint2* __restrict__ regions, int* __restrict__ nbs, float* __restrict__ outz)
{
    __shared__ unsigned ybf[2][16 * YSTR];   // double-buffered bf16 y tile, 2x4.25 KB
    __shared__ int lcnt;

    const int tid   = threadIdx.x;
    const int lane  = tid & 63;
    const int quad  = lane >> 4;
    const int l15   = lane & 15;
    const int wrow0 = tid & 192;             // wave_id*64
    const int col0  = blockIdx.x * CPB;

    if (blockIdx.x == 0 && tid == 0) outz[0] = 0.f;   // replaces memset dispatch
    if (tid == 0) lcnt = 0;

    // A fragments (x fp32 -> bf16, register-resident) + row-norm partials.
    bf16x8 af[4][4];
    float nrm[4];
#pragma unroll
    for (int mt = 0; mt < 4; ++mt) {
        const float* xp = x + (size_t)(wrow0 + mt * 16 + l15) * DDIM + quad * 8;
        float s2 = 0.f;
#pragma unroll
        for (int s = 0; s < 4; ++s) {
            const float4 a = *(const float4*)(xp + s * 32);
            const float4 b = *(const float4*)(xp + s * 32 + 4);
            s2 = fmaf(a.x, a.x, s2); s2 = fmaf(a.y, a.y, s2);
            s2 = fmaf(a.z, a.z, s2); s2 = fmaf(a.w, a.w, s2);
            s2 = fmaf(b.x, b.x, s2); s2 = fmaf(b.y, b.y, s2);
            s2 = fmaf(b.z, b.z, s2); s2 = fmaf(b.w, b.w, s2);
            const u32x4 t = pack8(a, b);
            af[mt][s] = __builtin_bit_cast(bf16x8, t);
        }
        nrm[mt] = s2;
    }
    float myThr[4];
#pragma unroll
    for (int mt = 0; mt < 4; ++mt) {
        float s2 = nrm[mt];
        s2 += __shfl_xor(s2, 16);
        s2 += __shfl_xor(s2, 32);
        myThr[mt] = ZGATE * sqrtf(s2);
    }
    float thrv[16];
#pragma unroll
    for (int mt = 0; mt < 4; ++mt)
#pragma unroll
        for (int r = 0; r < 4; ++r)
            thrv[mt * 4 + r] = __shfl(myThr[mt], quad * 4 + r);

    // staging: thread (sc,sj) loads 8 fp32 of y row col0+sc, converts, writes one b128
    const int sc = tid >> 4, sj = tid & 15;
    const float* ysrc = y + (size_t)(col0 + sc) * DDIM + sj * 8;
    const unsigned sdst = sc * YSTR + sj * 4;
    const unsigned frag_off = l15 * YSTR + quad * 4;

    // depth-1 prefetch, static scalars (R5 structure — best measured total)
    float4 ga = *(const float4*)(ysrc);
    float4 gb = *(const float4*)(ysrc + 4);
    *(u32x4*)(&ybf[0][0] + sdst) = pack8(ga, gb);   // stage tile 0

    for (int it = 0; it < NIT; ++it) {
        if (it + 1 < NIT) {                  // issue next tile's global loads early
            const float* yn = ysrc + (size_t)(it + 1) * 16 * DDIM;
            ga = *(const float4*)(yn);
            gb = *(const float4*)(yn + 4);
        }
        __syncthreads();                     // ybf[it&1] staged; prior reads of other buf done

        const unsigned* yb = &ybf[it & 1][0];
        bf16x8 bfrag[4];
#pragma unroll
        for (int s = 0; s < 4; ++s)
            bfrag[s] = __builtin_bit_cast(bf16x8, *(const u32x4*)(yb + frag_off + s * 16));

        f32x4 acc[4];
#pragma unroll
        for (int mt = 0; mt < 4; ++mt) acc[mt] = (f32x4){0.f, 0.f, 0.f, 0.f};
#pragma unroll
        for (int s = 0; s < 4; ++s)
#pragma unroll
            for (int mt = 0; mt < 4; ++mt)
                acc[mt] = __builtin_amdgcn_mfma_f32_16x16x32_bf16(af[mt][s], bfrag[s], acc[mt], 0, 0, 0);

        if (it + 1 < NIT)                    // convert + stage next tile (other buffer)
            *(u32x4*)(&ybf[(it + 1) & 1][0] + sdst) = pack8(ga, gb);

        // gate: lane's 16 acc values share col = col0+it*16+l15
        float m = -1.f;
#pragma unroll
        for (int mt = 0; mt < 4; ++mt)
#pragma unroll
            for (int r = 0; r < 4; ++r)
                m = fmaxf(m, acc[mt][r] - thrv[mt * 4 + r]);
        if (m > 0.f) {
            const int col = col0 + it * 16 + l15;
#pragma unroll
            for (int mt = 0; mt < 4; ++mt)
#pragma unroll
                for (int r = 0; r < 4; ++r) {
                    const float v = acc[mt][r];
                    if (v > thrv[mt * 4 + r]) {
                        const int idx = atomicAdd(&lcnt, 1);   // LDS atomic
                        if (idx < RCAP) {
                            const int row = wrow0 + mt * 16 + quad * 4 + r;
                            regions[blockIdx.x * RCAP + idx] =
                                make_uint2(__float_as_uint(v), ((unsigned)row << 17) | (unsigned)col);
                        }
                    }
                }
        }
    }

    __syncthreads();
    if (tid == 0) nbs[blockIdx.x] = lcnt;    // publish count once per block
}

// ---- helpers ----------------------------------------------------------------
__device__ __forceinline__ void insert5(float* t5, float v) {
    if (v > t5[K - 1]) {
        float nv = v;
#pragma unroll
        for (int p = 0; p < K; ++p) {
            const bool gt = nv > t5[p];
            const float tv = t5[p];
            if (gt) { t5[p] = nv; nv = tv; }
        }
    }
}

__device__ __forceinline__ void merge5(float* __restrict__ t5, const float* __restrict__ src) {
#pragma unroll
    for (int p = 0; p < K; ++p) insert5(t5, src[p]);
}

__device__ __forceinline__ float epilogue(const float* t5, float sp) {
    float loss[K], logit[K];
#pragma unroll
    for (int p = 0; p < K; ++p) {
        loss[p]  = fmaxf(0.f, t5[p] - sp + MARGIN);
        logit[p] = (loss[p] != 0.f) ? t5[p] : 0.f;   // sim_n * mask, as reference
    }
    float mx = logit[0];
#pragma unroll
    for (int p = 1; p < K; ++p) mx = fmaxf(mx, logit[p]);
    float den = 0.f, num = 0.f;
#pragma unroll
    for (int p = 0; p < K; ++p) {
        const float e = __expf(logit[p] - mx);
        den += e;
        num += loss[p] * e;
    }
    return num / den;
}

// ---- Pass 2: per-row top-5 + loss; exact fallback merged in ----------------
__global__ __launch_bounds__(256) void reduce_kernel(
    const float* __restrict__ x, const float* __restrict__ y,
    const int* __restrict__ pos,
    const uint2* __restrict__ regions, const int* __restrict__ nbs,
    float* __restrict__ out)
{
    const int row = blockIdx.x;
    const int tid = threadIdx.x;
    __shared__ float sred[256];
    __shared__ float sv[256 * K];
    __shared__ float xr[DDIM];
    __shared__ int sover, sok;
    if (tid == 0) { sover = 0; sok = 0; }

    // sim_p = fp32 dot(x[row], y[pos[row]]); also stage x row for fallback
    const int prow = pos[row];
    float p = 0.f;
    if (tid < DDIM) {
        const float xv = x[row * DDIM + tid];
        xr[tid] = xv;
        p = xv * y[(size_t)prow * DDIM + tid];
    }
    sred[tid] = p;
    __syncthreads();                          // also publishes sover/sok init
    for (int s = 128; s >= 1; s >>= 1) {
        if (tid < s) sred[tid] += sred[tid + s];
        __syncthreads();
    }

    // scan all 256 regions (one per thread; 256 KB total, L2-resident)
    float t5[K];
#pragma unroll
    for (int q = 0; q < K; ++q) t5[q] = -3.0e38f;
    int over = 0;
    {
        const int reg = tid;
        int nb = nbs[reg];
        if (nb > RCAP) { over = 1; nb = RCAP; }
        const uint2* rp = regions + (size_t)reg * RCAP;
        for (int i = 0; i < nb; ++i) {
            const uint2 e = rp[i];
            const int r = (int)(e.y >> 17), c = (int)(e.y & 0x1FFFFu);
            if (r == row && c != prow) insert5(t5, __uint_as_float(e.x));
        }
    }
    if (over) sover = 1;   // same-value race OK

#pragma unroll
    for (int q = 0; q < K; ++q) sv[tid * K + q] = t5[q];
    __syncthreads();
    for (int s = 128; s >= 1; s >>= 1) {
        if (tid < s) {
            merge5(t5, &sv[(tid + s) * K]);
#pragma unroll
            for (int q = 0; q < K; ++q) sv[tid * K + q] = t5[q];
        }
        __syncthreads();
    }

    if (tid == 0) {
        const bool ok = (sover == 0) && (t5[K - 1] > -1.0e38f);
        sok = ok ? 1 : 0;
        if (ok) atomicAdd(out, epilogue(t5, sred[0]) * (1.0f / (BROWS * K)));
    }
    __syncthreads();
    if (sok) return;

    // ---- exactness insurance: brute-force this row (dormant in practice) ----
    float b5[K];
#pragma unroll
    for (int q = 0; q < K; ++q) b5[q] = -3.0e38f;
    for (int col = tid; col < NCOLS; col += 256) {
        if (col == prow) continue;
        const float* yp = y + (size_t)col * DDIM;
        float d = 0.f;
        for (int k = 0; k < DDIM; ++k) d = fmaf(xr[k], yp[k], d);
        insert5(b5, d);
    }
#pragma unroll
    for (int q = 0; q < K; ++q) sv[tid * K + q] = b5[q];
    __syncthreads();
    for (int s = 128; s >= 1; s >>= 1) {
        if (tid < s) {
            merge5(b5, &sv[(tid + s) * K]);
#pragma unroll
            for (int q = 0; q < K; ++q) sv[tid * K + q] = b5[q];
        }
        __syncthreads();
    }
    if (tid == 0) atomicAdd(out, epilogue(b5, sred[0]) * (1.0f / (BROWS * K)));
}

extern "C" void kernel_launch(void* const* d_in, const int* in_sizes, int n_in,
                              void* d_out, int out_size, void* d_ws, size_t ws_size,
                              hipStream_t stream) {
    const float* x  = (const float*)d_in[0];   // [256,128] fp32
    const float* y  = (const float*)d_in[1];   // [131072,128] fp32
    // d_in[2] (target) is redundant (one-hot of pos_inds) — never read.
    const int* pos  = (const int*)d_in[3];     // [256] int32
    // d_in[4] (num_neg) fixed at 5 — compile-time K.

    uint2* regions = (uint2*)d_ws;                           // 256*128*8 B = 256 KB
    int*   nbs     = (int*)(regions + (size_t)NBLK * RCAP);  // 256 ints

    gemm_collect_kernel<<<dim3(NBLK), 256, 0, stream>>>(x, y, regions, nbs, (float*)d_out);
    reduce_kernel<<<dim3(BROWS), 256, 0, stream>>>(x, y, pos, regions, nbs, (float*)d_out);
}